// Round 14
// baseline (77.369 us; speedup 1.0000x reference)
//
#include <hip/hip_runtime.h>
#include <hip/hip_bf16.h>

typedef __attribute__((ext_vector_type(8))) short short8;
typedef __attribute__((ext_vector_type(4))) float f32x4;
typedef __attribute__((ext_vector_type(4))) unsigned int u32x4;
typedef __attribute__((ext_vector_type(2))) unsigned int u32x2;

#define DFEAT 128
#define LDZ 136    // z-tile row stride (shorts): 272B rows -> <=2-way banks on b128

// Raw barrier WITHOUT the compiler's vmcnt(0) drain (__syncthreads would
// force-retire cross-iteration prefetch). lgkmcnt(0) makes this thread's
// ds_write visible; s_barrier orders threads.
#define LGKM_BARRIER() do {                                   \
    asm volatile("s_waitcnt lgkmcnt(0)" ::: "memory");        \
    __builtin_amdgcn_sched_barrier(0);                        \
    __builtin_amdgcn_s_barrier();                             \
    __builtin_amdgcn_sched_barrier(0);                        \
} while (0)

__device__ __forceinline__ unsigned short f2bf(float f) {
    unsigned int u = __float_as_uint(f);
    u += 0x7FFFu + ((u >> 16) & 1u);   // round-nearest-even
    return (unsigned short)(u >> 16);
}
// packed f32x2 -> bf16x2, RNE (gfx950 v_cvt_pk_bf16_f32)
__device__ __forceinline__ unsigned int cvt2(float lo, float hi) {
    unsigned int r;
    asm("v_cvt_pk_bf16_f32 %0, %1, %2" : "=v"(r) : "v"(lo), "v"(hi));
    return r;
}
__device__ __forceinline__ float bf2f(unsigned int bits) {
    return __uint_as_float(bits << 16);
}

// node_gemm v9 = round-13 v8 with W LDS staging ELIMINATED.
// Rationale: rounds 11-13 proved load latency is already hidden (loads retire
// ~9000 cyc after issue) — the binding limit is concurrency: the dead-after-
// prologue 34.8KB W-staging buffer capped residency at 4 blocks/CU (16/32
// waves). Now each wave builds its 8 W^T fragments straight from global
// (64 scalar fp32 reads/thread, W is 128KB -> L2/L3 resident), LDS = 8.7KB
// z double-buffer only -> 8 blocks/CU (32/32 waves), grid doubled.
// VMEM accounting per thread per iter (in-order): 2 loads then 2 stores.
//   prologue: vmcnt(0) clears W/bias loads; A(2)+B(2) -> vmcnt(2) retires A.
//   peeled iter0: queue B,A',S -> vmcnt(4) retires B.
//   steady: queue Lprev,Sprev,Lthis,Sthis -> vmcnt(6) retires exactly Lprev.
// Loads always issued (clamped addr) -> uniform counts; stores uniform since
// launcher guards nN % 16 == 0. Trip count block-uniform -> raw barrier safe.
__global__ __launch_bounds__(256) void node_gemm(
    const float* __restrict__ zi, const float* __restrict__ zj,
    const float* __restrict__ W1, const float* __restrict__ b1,
    unsigned short* __restrict__ Aout, unsigned short* __restrict__ Bout,
    int nN)
{
    __shared__ unsigned short zb[2][16][LDZ];   // 8704 B total

    const int table = blockIdx.y;
    const float* __restrict__ z = table ? zj : zi;
    unsigned short* __restrict__ outp = table ? Bout : Aout;
    const int tid = threadIdx.x;

    const int lane = tid & 63;
    const int l15  = lane & 15;
    const int kg   = lane >> 4;
    const int w    = tid >> 6;
    const int cbase = w * 32;

    // --- prologue: build this wave's W^T fragments from global (no LDS) ---
    // wf[ci][kk][j] = bf16( W1[(table*128 + kk*32 + kg*8 + j)*128 + cbase+ci*16+l15] )
    short8 wf[2][4];
#pragma unroll
    for (int ci = 0; ci < 2; ++ci) {
        const float* wcol = W1 + (size_t)(table * 128) * DFEAT + (cbase + ci * 16 + l15);
#pragma unroll
        for (int kk = 0; kk < 4; ++kk) {
            const float* wp = wcol + (size_t)(kk * 32 + kg * 8) * DFEAT;
            short8 f;
#pragma unroll
            for (int j = 0; j < 8; ++j)
                f[j] = (short)f2bf(wp[(size_t)j * DFEAT]);
            wf[ci][kk] = f;
        }
    }
    f32x4 biasv[2];
    if (table == 0) {
#pragma unroll
        for (int ci = 0; ci < 2; ++ci)
            biasv[ci] = *(const f32x4*)&b1[cbase + ci * 16 + kg * 4];
    } else {
        biasv[0] = (f32x4){0.f, 0.f, 0.f, 0.f};
        biasv[1] = (f32x4){0.f, 0.f, 0.f, 0.f};
    }

    const int nStrips = (nN + 15) >> 4;
    const int G = gridDim.x;
    const int r    = tid >> 4;           // staging row 0..15
    const int coff = (tid & 15) * 8;     // staging col (8-elem units)

    auto gaddr = [&](int s) {
        int row = s * 16 + r;
        if (row >= nN) row = nN - 1;     // clamp: issued loads always legal
        return z + (size_t)row * DFEAT + coff;
    };

    f32x4 t0A, t1A, t0B, t1B;
    auto issueA = [&](int s) {
        const float* gp = gaddr(s);
        asm volatile("global_load_dwordx4 %0, %1, off"           : "=&v"(t0A) : "v"(gp) : "memory");
        asm volatile("global_load_dwordx4 %0, %1, off offset:16" : "=&v"(t1A) : "v"(gp) : "memory");
    };
    auto issueB = [&](int s) {
        const float* gp = gaddr(s);
        asm volatile("global_load_dwordx4 %0, %1, off"           : "=&v"(t0B) : "v"(gp) : "memory");
        asm volatile("global_load_dwordx4 %0, %1, off offset:16" : "=&v"(t1B) : "v"(gp) : "memory");
    };
    auto writeA = [&](int buf) {
        u32x4 v;
        v[0] = cvt2(t0A[0], t0A[1]); v[1] = cvt2(t0A[2], t0A[3]);
        v[2] = cvt2(t1A[0], t1A[1]); v[3] = cvt2(t1A[2], t1A[3]);
        *(u32x4*)&zb[buf][r][coff] = v;
    };
    auto writeB = [&](int buf) {
        u32x4 v;
        v[0] = cvt2(t0B[0], t0B[1]); v[1] = cvt2(t0B[2], t0B[3]);
        v[2] = cvt2(t1B[0], t1B[1]); v[3] = cvt2(t1B[2], t1B[3]);
        *(u32x4*)&zb[buf][r][coff] = v;
    };
    auto compute = [&](int s, int buf) {
        f32x4 acc0 = biasv[0], acc1 = biasv[1];
#pragma unroll
        for (int kk = 0; kk < 4; ++kk) {
            short8 zf = *(const short8*)&zb[buf][l15][kk * 32 + kg * 8];
            acc0 = __builtin_amdgcn_mfma_f32_16x16x32_bf16(wf[0][kk], zf, acc0, 0, 0, 0);
            acc1 = __builtin_amdgcn_mfma_f32_16x16x32_bf16(wf[1][kk], zf, acc1, 0, 0, 0);
        }
        int row = s * 16 + l15;
        if (row < nN) {
            unsigned short* op = outp + (size_t)row * DFEAT + cbase + kg * 4;
            u32x2 v0; v0[0] = cvt2(acc0[0], acc0[1]); v0[1] = cvt2(acc0[2], acc0[3]);
            *(u32x2*)op = v0;
            u32x2 v1; v1[0] = cvt2(acc1[0], acc1[1]); v1[1] = cvt2(acc1[2], acc1[3]);
            *(u32x2*)(op + 16) = v1;
        }
    };

    int s = blockIdx.x;
    // clear compiler-managed prologue loads from the VMEM queue, then prime
    asm volatile("s_waitcnt vmcnt(0)" ::: "memory");
    __builtin_amdgcn_sched_barrier(0);
    issueA(s);
    issueB(s + G);
    asm volatile("s_waitcnt vmcnt(2)" ::: "memory");   // retire A (B stays in flight)
    __builtin_amdgcn_sched_barrier(0);
    writeA(0);
    LGKM_BARRIER();

    if (s < nStrips) {
        // peeled iter0: compute s (buf0); A free -> issue s+2G
        issueA(s + 2 * G);
        compute(s, 0);
        asm volatile("s_waitcnt vmcnt(4)" ::: "memory");   // retire B
        __builtin_amdgcn_sched_barrier(0);
        writeB(1);
        LGKM_BARRIER();

        int sc = s + G;
        while (sc < nStrips) {
            // odd iter: compute sc (buf1); B free -> issue sc+2G; wait A
            issueB(sc + 2 * G);
            compute(sc, 1);
            asm volatile("s_waitcnt vmcnt(6)" ::: "memory");
            __builtin_amdgcn_sched_barrier(0);
            writeA(0);
            LGKM_BARRIER();
            sc += G;
            if (sc >= nStrips) break;
            // even iter: compute sc (buf0); A free -> issue sc+2G; wait B
            issueA(sc + 2 * G);
            compute(sc, 0);
            asm volatile("s_waitcnt vmcnt(6)" ::: "memory");
            __builtin_amdgcn_sched_barrier(0);
            writeB(1);
            LGKM_BARRIER();
            sc += G;
        }
    }
}

// Phase 2 (round-12, at gather roofline ~45.5us): 16 lanes/edge,
// 4 quads = 16 edges/wave/iter.
__global__ __launch_bounds__(256) void edge_kernel(
    const unsigned short* __restrict__ A, const unsigned short* __restrict__ B,
    const int* __restrict__ src, const int* __restrict__ dst,
    const float* __restrict__ W3, const float* __restrict__ b3,
    float* __restrict__ out, int nE)
{
    const int lane = threadIdx.x & 63;
    const int sub  = lane & 15;
    const int grp  = lane >> 4;

    float w3v[8];
#pragma unroll
    for (int j = 0; j < 8; ++j) w3v[j] = W3[sub * 8 + j];
    const float bb = b3[0];

    int wv = blockIdx.x * 4 + (threadIdx.x >> 6);
    int nw = gridDim.x * 4;

    for (int base = wv * 16; base < nE; base += nw * 16) {
        int e0 = base + grp;
        int e1 = base + 4 + grp;
        int e2 = base + 8 + grp;
        int e3 = base + 12 + grp;
        bool v0 = e0 < nE, v1 = e1 < nE, v2 = e2 < nE, v3 = e3 < nE;
        int s0 = v0 ? src[e0] : 0, d0 = v0 ? dst[e0] : 0;
        int s1 = v1 ? src[e1] : 0, d1 = v1 ? dst[e1] : 0;
        int s2 = v2 ? src[e2] : 0, d2 = v2 ? dst[e2] : 0;
        int s3 = v3 ? src[e3] : 0, d3 = v3 ? dst[e3] : 0;

        u32x4 av0 = *(const u32x4*)(A + (size_t)s0 * DFEAT + sub * 8);
        u32x4 bv0 = *(const u32x4*)(B + (size_t)d0 * DFEAT + sub * 8);
        u32x4 av1 = *(const u32x4*)(A + (size_t)s1 * DFEAT + sub * 8);
        u32x4 bv1 = *(const u32x4*)(B + (size_t)d1 * DFEAT + sub * 8);
        u32x4 av2 = *(const u32x4*)(A + (size_t)s2 * DFEAT + sub * 8);
        u32x4 bv2 = *(const u32x4*)(B + (size_t)d2 * DFEAT + sub * 8);
        u32x4 av3 = *(const u32x4*)(A + (size_t)s3 * DFEAT + sub * 8);
        u32x4 bv3 = *(const u32x4*)(B + (size_t)d3 * DFEAT + sub * 8);

        float p0 = 0.f, p1 = 0.f, p2 = 0.f, p3 = 0.f;
#pragma unroll
        for (int w = 0; w < 4; ++w) {
            float wa = w3v[w * 2], wbv = w3v[w * 2 + 1];
            p0 = fmaf(fmaxf(bf2f(av0[w] & 0xFFFFu) + bf2f(bv0[w] & 0xFFFFu), 0.f), wa, p0);
            p0 = fmaf(fmaxf(bf2f(av0[w] >> 16)     + bf2f(bv0[w] >> 16),     0.f), wbv, p0);
            p1 = fmaf(fmaxf(bf2f(av1[w] & 0xFFFFu) + bf2f(bv1[w] & 0xFFFFu), 0.f), wa, p1);
            p1 = fmaf(fmaxf(bf2f(av1[w] >> 16)     + bf2f(bv1[w] >> 16),     0.f), wbv, p1);
            p2 = fmaf(fmaxf(bf2f(av2[w] & 0xFFFFu) + bf2f(bv2[w] & 0xFFFFu), 0.f), wa, p2);
            p2 = fmaf(fmaxf(bf2f(av2[w] >> 16)     + bf2f(bv2[w] >> 16),     0.f), wbv, p2);
            p3 = fmaf(fmaxf(bf2f(av3[w] & 0xFFFFu) + bf2f(bv3[w] & 0xFFFFu), 0.f), wa, p3);
            p3 = fmaf(fmaxf(bf2f(av3[w] >> 16)     + bf2f(bv3[w] >> 16),     0.f), wbv, p3);
        }
#pragma unroll
        for (int off = 8; off > 0; off >>= 1) {
            p0 += __shfl_xor(p0, off, 64);
            p1 += __shfl_xor(p1, off, 64);
            p2 += __shfl_xor(p2, off, 64);
            p3 += __shfl_xor(p3, off, 64);
        }
        if (sub == 0) {
            if (v0) out[e0] = 1.f / (1.f + __expf(-(p0 + bb)));
            if (v1) out[e1] = 1.f / (1.f + __expf(-(p1 + bb)));
            if (v2) out[e2] = 1.f / (1.f + __expf(-(p2 + bb)));
            if (v3) out[e3] = 1.f / (1.f + __expf(-(p3 + bb)));
        }
    }
}

// Fallback (only if d_ws too small / nN not multiple of 16): slow, correct.
__global__ __launch_bounds__(256) void fallback_kernel(
    const float* __restrict__ zi, const float* __restrict__ zj,
    const int* __restrict__ src, const int* __restrict__ dst,
    const float* __restrict__ W1, const float* __restrict__ b1,
    const float* __restrict__ W3, const float* __restrict__ b3,
    float* __restrict__ out, int nE)
{
    int e = blockIdx.x * blockDim.x + threadIdx.x;
    if (e >= nE) return;
    const float* a = zi + (size_t)src[e] * DFEAT;
    const float* b = zj + (size_t)dst[e] * DFEAT;
    float logit = b3[0];
    for (int h = 0; h < 128; ++h) {
        float acc = b1[h];
        for (int k = 0; k < 128; ++k) acc = fmaf(a[k], W1[(size_t)k * 128 + h], acc);
        for (int k = 0; k < 128; ++k) acc = fmaf(b[k], W1[(size_t)(128 + k) * 128 + h], acc);
        if (acc > 0.f) logit = fmaf(acc, W3[h], logit);
    }
    out[e] = 1.f / (1.f + __expf(-logit));
}

extern "C" void kernel_launch(void* const* d_in, const int* in_sizes, int n_in,
                              void* d_out, int out_size, void* d_ws, size_t ws_size,
                              hipStream_t stream) {
    const float* zi = (const float*)d_in[0];
    const float* zj = (const float*)d_in[1];
    const int*  src = (const int*)d_in[2];
    const int*  dst = (const int*)d_in[3];
    const float* W1 = (const float*)d_in[4];
    const float* b1 = (const float*)d_in[5];
    const float* W3 = (const float*)d_in[6];
    const float* b3 = (const float*)d_in[7];
    float* out = (float*)d_out;

    int nN = in_sizes[0] / DFEAT;
    int nE = in_sizes[2];
    size_t abytes = (size_t)nN * DFEAT * sizeof(unsigned short);

    if (ws_size >= 2 * abytes && (nN & 15) == 0) {
        unsigned short* A = (unsigned short*)d_ws;
        unsigned short* B = A + (size_t)nN * DFEAT;
        // 1024x2 = 2048 blocks = 8/CU (32 waves/CU, LDS 8.7KB); ~6 strips/block
        dim3 g1(1024, 2, 1);
        node_gemm<<<g1, 256, 0, stream>>>(zi, zj, W1, b1, A, B, nN);
        edge_kernel<<<2048, 256, 0, stream>>>(A, B, src, dst, W3, b3, out, nE);
    } else {
        fallback_kernel<<<(nE + 255) / 256, 256, 0, stream>>>(
            zi, zj, src, dst, W1, b1, W3, b3, out, nE);
    }
}

// Round 15
// 76.913 us; speedup vs baseline: 1.0059x; 1.0059x over previous
//
#include <hip/hip_runtime.h>
#include <hip/hip_bf16.h>

typedef __attribute__((ext_vector_type(8))) short short8;
typedef __attribute__((ext_vector_type(4))) float f32x4;
typedef __attribute__((ext_vector_type(4))) unsigned int u32x4;
typedef __attribute__((ext_vector_type(2))) unsigned int u32x2;

#define DFEAT 128
#define LDZ 136    // z-tile row stride (shorts): 272B rows -> <=2-way banks on b128

// Raw barrier WITHOUT the compiler's vmcnt(0) drain.
#define LGKM_BARRIER() do {                                   \
    asm volatile("s_waitcnt lgkmcnt(0)" ::: "memory");        \
    __builtin_amdgcn_sched_barrier(0);                        \
    __builtin_amdgcn_s_barrier();                             \
    __builtin_amdgcn_sched_barrier(0);                        \
} while (0)

__device__ __forceinline__ unsigned short f2bf(float f) {
    unsigned int u = __float_as_uint(f);
    u += 0x7FFFu + ((u >> 16) & 1u);   // round-nearest-even
    return (unsigned short)(u >> 16);
}
// packed f32x2 -> bf16x2, RNE (gfx950 v_cvt_pk_bf16_f32)
__device__ __forceinline__ unsigned int cvt2(float lo, float hi) {
    unsigned int r;
    asm("v_cvt_pk_bf16_f32 %0, %1, %2" : "=v"(r) : "v"(lo), "v"(hi));
    return r;
}
__device__ __forceinline__ float bf2f(unsigned int bits) {
    return __uint_as_float(bits << 16);
}

// node_gemm v10 = v9 with the SECOND transit pair removed.
// Diagnosis r14: VGPR=68 crossed the 64-reg occupancy boundary -> still only
// 16 waves/CU despite 8.7KB LDS. r12 proved 2-deep vs 1-deep transit is
// perf-neutral, so pair B was pure register cost. 1-deep accounting
// (round-11 scheme, proven correct): per iter
//   issue L(next) -> compute(cur): 2 stores -> s_waitcnt vmcnt(2) -> write
//   -> LGKM_BARRIER.
// At the wait, queue (in-order) <= [S_prev(2), L_next(2), S_cur(2)];
// vmcnt(2) retires S_prev+L_next, leaving S_cur -> write's data is ready.
// Loads always issued (clamped) -> uniform counts; stores uniform because
// launcher guards nN % 16 == 0. Trip count block-uniform -> raw barrier safe.
// Target: VGPR <= 64 -> 8 blocks/CU (32 waves) with grid 2048 = 8 x 256.
__global__ __launch_bounds__(256) void node_gemm(
    const float* __restrict__ zi, const float* __restrict__ zj,
    const float* __restrict__ W1, const float* __restrict__ b1,
    unsigned short* __restrict__ Aout, unsigned short* __restrict__ Bout,
    int nN)
{
    __shared__ unsigned short zb[2][16][LDZ];   // 8704 B total

    const int table = blockIdx.y;
    const float* __restrict__ z = table ? zj : zi;
    unsigned short* __restrict__ outp = table ? Bout : Aout;
    const int tid = threadIdx.x;

    const int lane = tid & 63;
    const int l15  = lane & 15;
    const int kg   = lane >> 4;
    const int w    = tid >> 6;
    const int cbase = w * 32;

    // --- prologue: build this wave's W^T fragments from global (no LDS) ---
    short8 wf[2][4];
#pragma unroll
    for (int ci = 0; ci < 2; ++ci) {
        const float* wcol = W1 + (size_t)(table * 128) * DFEAT + (cbase + ci * 16 + l15);
#pragma unroll
        for (int kk = 0; kk < 4; ++kk) {
            const float* wp = wcol + (size_t)(kk * 32 + kg * 8) * DFEAT;
            short8 f;
#pragma unroll
            for (int j = 0; j < 8; ++j)
                f[j] = (short)f2bf(wp[(size_t)j * DFEAT]);
            wf[ci][kk] = f;
        }
    }
    f32x4 biasv[2];
    if (table == 0) {
#pragma unroll
        for (int ci = 0; ci < 2; ++ci)
            biasv[ci] = *(const f32x4*)&b1[cbase + ci * 16 + kg * 4];
    } else {
        biasv[0] = (f32x4){0.f, 0.f, 0.f, 0.f};
        biasv[1] = (f32x4){0.f, 0.f, 0.f, 0.f};
    }

    const int nStrips = (nN + 15) >> 4;
    const int G = gridDim.x;
    const int r    = tid >> 4;           // staging row 0..15
    const int coff = (tid & 15) * 8;     // staging col (8-elem units)

    auto gaddr = [&](int s) {
        int row = s * 16 + r;
        if (row >= nN) row = nN - 1;     // clamp: issued loads always legal
        return z + (size_t)row * DFEAT + coff;
    };

    f32x4 t0, t1;
    auto issue = [&](int s) {
        const float* gp = gaddr(s);
        asm volatile("global_load_dwordx4 %0, %1, off"           : "=&v"(t0) : "v"(gp) : "memory");
        asm volatile("global_load_dwordx4 %0, %1, off offset:16" : "=&v"(t1) : "v"(gp) : "memory");
    };
    auto write_tile = [&](int buf) {
        u32x4 v;
        v[0] = cvt2(t0[0], t0[1]); v[1] = cvt2(t0[2], t0[3]);
        v[2] = cvt2(t1[0], t1[1]); v[3] = cvt2(t1[2], t1[3]);
        *(u32x4*)&zb[buf][r][coff] = v;
    };
    auto compute = [&](int s, int buf) {
        f32x4 acc0 = biasv[0], acc1 = biasv[1];
#pragma unroll
        for (int kk = 0; kk < 4; ++kk) {
            short8 zf = *(const short8*)&zb[buf][l15][kk * 32 + kg * 8];
            acc0 = __builtin_amdgcn_mfma_f32_16x16x32_bf16(wf[0][kk], zf, acc0, 0, 0, 0);
            acc1 = __builtin_amdgcn_mfma_f32_16x16x32_bf16(wf[1][kk], zf, acc1, 0, 0, 0);
        }
        int row = s * 16 + l15;
        if (row < nN) {
            unsigned short* op = outp + (size_t)row * DFEAT + cbase + kg * 4;
            u32x2 v0; v0[0] = cvt2(acc0[0], acc0[1]); v0[1] = cvt2(acc0[2], acc0[3]);
            *(u32x2*)op = v0;
            u32x2 v1; v1[0] = cvt2(acc1[0], acc1[1]); v1[1] = cvt2(acc1[2], acc1[3]);
            *(u32x2*)(op + 16) = v1;
        }
    };

    int s = blockIdx.x;
    // clear compiler-managed prologue loads, then prime buf0
    asm volatile("s_waitcnt vmcnt(0)" ::: "memory");
    __builtin_amdgcn_sched_barrier(0);
    issue(s);
    asm volatile("s_waitcnt vmcnt(0)" ::: "memory");
    __builtin_amdgcn_sched_barrier(0);
    write_tile(0);
    LGKM_BARRIER();

    int buf = 0;
    while (s < nStrips) {
        issue(s + G);                    // loads for next strip
        compute(s, buf);                 // MFMA + 2 stores for current strip
        asm volatile("s_waitcnt vmcnt(2)" ::: "memory");  // retire S_prev + L_next
        __builtin_amdgcn_sched_barrier(0);
        write_tile(buf ^ 1);
        LGKM_BARRIER();
        buf ^= 1;
        s += G;
    }
}

// Phase 2 (round-12, at gather roofline ~45.5us): 16 lanes/edge,
// 4 quads = 16 edges/wave/iter.
__global__ __launch_bounds__(256) void edge_kernel(
    const unsigned short* __restrict__ A, const unsigned short* __restrict__ B,
    const int* __restrict__ src, const int* __restrict__ dst,
    const float* __restrict__ W3, const float* __restrict__ b3,
    float* __restrict__ out, int nE)
{
    const int lane = threadIdx.x & 63;
    const int sub  = lane & 15;
    const int grp  = lane >> 4;

    float w3v[8];
#pragma unroll
    for (int j = 0; j < 8; ++j) w3v[j] = W3[sub * 8 + j];
    const float bb = b3[0];

    int wv = blockIdx.x * 4 + (threadIdx.x >> 6);
    int nw = gridDim.x * 4;

    for (int base = wv * 16; base < nE; base += nw * 16) {
        int e0 = base + grp;
        int e1 = base + 4 + grp;
        int e2 = base + 8 + grp;
        int e3 = base + 12 + grp;
        bool v0 = e0 < nE, v1 = e1 < nE, v2 = e2 < nE, v3 = e3 < nE;
        int s0 = v0 ? src[e0] : 0, d0 = v0 ? dst[e0] : 0;
        int s1 = v1 ? src[e1] : 0, d1 = v1 ? dst[e1] : 0;
        int s2 = v2 ? src[e2] : 0, d2 = v2 ? dst[e2] : 0;
        int s3 = v3 ? src[e3] : 0, d3 = v3 ? dst[e3] : 0;

        u32x4 av0 = *(const u32x4*)(A + (size_t)s0 * DFEAT + sub * 8);
        u32x4 bv0 = *(const u32x4*)(B + (size_t)d0 * DFEAT + sub * 8);
        u32x4 av1 = *(const u32x4*)(A + (size_t)s1 * DFEAT + sub * 8);
        u32x4 bv1 = *(const u32x4*)(B + (size_t)d1 * DFEAT + sub * 8);
        u32x4 av2 = *(const u32x4*)(A + (size_t)s2 * DFEAT + sub * 8);
        u32x4 bv2 = *(const u32x4*)(B + (size_t)d2 * DFEAT + sub * 8);
        u32x4 av3 = *(const u32x4*)(A + (size_t)s3 * DFEAT + sub * 8);
        u32x4 bv3 = *(const u32x4*)(B + (size_t)d3 * DFEAT + sub * 8);

        float p0 = 0.f, p1 = 0.f, p2 = 0.f, p3 = 0.f;
#pragma unroll
        for (int w = 0; w < 4; ++w) {
            float wa = w3v[w * 2], wbv = w3v[w * 2 + 1];
            p0 = fmaf(fmaxf(bf2f(av0[w] & 0xFFFFu) + bf2f(bv0[w] & 0xFFFFu), 0.f), wa, p0);
            p0 = fmaf(fmaxf(bf2f(av0[w] >> 16)     + bf2f(bv0[w] >> 16),     0.f), wbv, p0);
            p1 = fmaf(fmaxf(bf2f(av1[w] & 0xFFFFu) + bf2f(bv1[w] & 0xFFFFu), 0.f), wa, p1);
            p1 = fmaf(fmaxf(bf2f(av1[w] >> 16)     + bf2f(bv1[w] >> 16),     0.f), wbv, p1);
            p2 = fmaf(fmaxf(bf2f(av2[w] & 0xFFFFu) + bf2f(bv2[w] & 0xFFFFu), 0.f), wa, p2);
            p2 = fmaf(fmaxf(bf2f(av2[w] >> 16)     + bf2f(bv2[w] >> 16),     0.f), wbv, p2);
            p3 = fmaf(fmaxf(bf2f(av3[w] & 0xFFFFu) + bf2f(bv3[w] & 0xFFFFu), 0.f), wa, p3);
            p3 = fmaf(fmaxf(bf2f(av3[w] >> 16)     + bf2f(bv3[w] >> 16),     0.f), wbv, p3);
        }
#pragma unroll
        for (int off = 8; off > 0; off >>= 1) {
            p0 += __shfl_xor(p0, off, 64);
            p1 += __shfl_xor(p1, off, 64);
            p2 += __shfl_xor(p2, off, 64);
            p3 += __shfl_xor(p3, off, 64);
        }
        if (sub == 0) {
            if (v0) out[e0] = 1.f / (1.f + __expf(-(p0 + bb)));
            if (v1) out[e1] = 1.f / (1.f + __expf(-(p1 + bb)));
            if (v2) out[e2] = 1.f / (1.f + __expf(-(p2 + bb)));
            if (v3) out[e3] = 1.f / (1.f + __expf(-(p3 + bb)));
        }
    }
}

// Fallback (only if d_ws too small / nN not multiple of 16): slow, correct.
__global__ __launch_bounds__(256) void fallback_kernel(
    const float* __restrict__ zi, const float* __restrict__ zj,
    const int* __restrict__ src, const int* __restrict__ dst,
    const float* __restrict__ W1, const float* __restrict__ b1,
    const float* __restrict__ W3, const float* __restrict__ b3,
    float* __restrict__ out, int nE)
{
    int e = blockIdx.x * blockDim.x + threadIdx.x;
    if (e >= nE) return;
    const float* a = zi + (size_t)src[e] * DFEAT;
    const float* b = zj + (size_t)dst[e] * DFEAT;
    float logit = b3[0];
    for (int h = 0; h < 128; ++h) {
        float acc = b1[h];
        for (int k = 0; k < 128; ++k) acc = fmaf(a[k], W1[(size_t)k * 128 + h], acc);
        for (int k = 0; k < 128; ++k) acc = fmaf(b[k], W1[(size_t)(128 + k) * 128 + h], acc);
        if (acc > 0.f) logit = fmaf(acc, W3[h], logit);
    }
    out[e] = 1.f / (1.f + __expf(-logit));
}

extern "C" void kernel_launch(void* const* d_in, const int* in_sizes, int n_in,
                              void* d_out, int out_size, void* d_ws, size_t ws_size,
                              hipStream_t stream) {
    const float* zi = (const float*)d_in[0];
    const float* zj = (const float*)d_in[1];
    const int*  src = (const int*)d_in[2];
    const int*  dst = (const int*)d_in[3];
    const float* W1 = (const float*)d_in[4];
    const float* b1 = (const float*)d_in[5];
    const float* W3 = (const float*)d_in[6];
    const float* b3 = (const float*)d_in[7];
    float* out = (float*)d_out;

    int nN = in_sizes[0] / DFEAT;
    int nE = in_sizes[2];
    size_t abytes = (size_t)nN * DFEAT * sizeof(unsigned short);

    if (ws_size >= 2 * abytes && (nN & 15) == 0) {
        unsigned short* A = (unsigned short*)d_ws;
        unsigned short* B = A + (size_t)nN * DFEAT;
        // 1024x2 = 2048 blocks; with VGPR<=64 and LDS 8.7KB -> 8 blocks/CU
        dim3 g1(1024, 2, 1);
        node_gemm<<<g1, 256, 0, stream>>>(zi, zj, W1, b1, A, B, nN);
        edge_kernel<<<2048, 256, 0, stream>>>(A, B, src, dst, W3, b3, out, nE);
    } else {
        fallback_kernel<<<(nE + 255) / 256, 256, 0, stream>>>(
            zi, zj, src, dst, W1, b1, W3, b3, out, nE);
    }
}